// Round 2
// baseline (111.269 us; speedup 1.0000x reference)
//
#include <hip/hip_runtime.h>
#include <hip/hip_bf16.h>

#define NN 12288
#define ED 256
#define ES 32
#define NE (2*NN - 1)   // N self-loops + N-1 parent->child edges

typedef __hip_bfloat16 bf16;

__device__ __forceinline__ float ldf(const void* p, int i, int f32) {
    return f32 ? ((const float*)p)[i]
               : __bfloat162float(((const bf16*)p)[i]);
}

// Detect storage dtype of float tensors. If W1 is really float32, its bf16
// reinterpretation contains mantissa-bit words with random exponents -> huge
// magnitudes. If genuinely bf16, all |v| <~ 1.5. Sets *flag=1 for f32.
__global__ void k_detect(const void* __restrict__ W1, int* __restrict__ flag) {
    const bf16* p = (const bf16*)W1;
    bool huge = false;
    for (int k = threadIdx.x; k < 512; k += 256) {   // 1 KB read: safe for either dtype
        float v = __bfloat162float(p[k]);
        if (v > 1e4f || v < -1e4f) huge = true;
    }
    if (huge) atomicOr(flag, 1);
}

// Fused: (a) degree = row-count of edge list via atomics, (b) X1 = emb@W1 + b1.
// tid = n*32 + j. Grid is exactly NN*ES threads.
__global__ void k_deg_x1(const int* __restrict__ node_ids,
                         const int* __restrict__ edges,
                         const void* __restrict__ table,
                         const void* __restrict__ W1,
                         const void* __restrict__ b1,
                         const int* __restrict__ flag,
                         unsigned int* __restrict__ deg,
                         float* __restrict__ X1) {
    int tid = blockIdx.x * blockDim.x + threadIdx.x;
    if (tid < NE) atomicAdd(&deg[edges[2 * tid]], 1u);
    int f32 = *flag;
    int n = tid >> 5, j = tid & 31;
    float acc = ldf(b1, j, f32);
    if (f32) {
        const float* e = (const float*)table + (size_t)node_ids[n] * ED;
        const float* w = (const float*)W1;
        #pragma unroll 8
        for (int k = 0; k < ED; ++k) acc += e[k] * w[k * ES + j];
    } else {
        const bf16* e = (const bf16*)table + (size_t)node_ids[n] * ED;
        const bf16* w = (const bf16*)W1;
        #pragma unroll 8
        for (int k = 0; k < ED; ++k)
            acc += __bfloat162float(e[k]) * __bfloat162float(w[k * ES + j]);
    }
    X1[tid] = acc;
}

// acc[r,:] += d[r]*d[c]*X[c,:] per edge (r,c); 32 threads per edge.
__global__ void k_scatter(const int* __restrict__ edges,
                          const unsigned int* __restrict__ deg,
                          const float* __restrict__ X,
                          float* __restrict__ acc) {
    int tid = blockIdx.x * blockDim.x + threadIdx.x;
    if (tid >= NE * ES) return;
    int e = tid >> 5, k = tid & 31;
    int r = edges[2 * e], c = edges[2 * e + 1];
    float w = rsqrtf((float)deg[r]) * rsqrtf((float)deg[c]);
    atomicAdd(&acc[r * ES + k], w * X[c * ES + k]);
}

// X2 = relu(acc1) @ W2 + b2
__global__ void k_x2(const float* __restrict__ acc1,
                     const void* __restrict__ W2,
                     const void* __restrict__ b2,
                     const int* __restrict__ flag,
                     float* __restrict__ X2) {
    int tid = blockIdx.x * blockDim.x + threadIdx.x;
    int f32 = *flag;
    int n = tid >> 5, j = tid & 31;
    float acc = ldf(b2, j, f32);
    if (f32) {
        const float* w = (const float*)W2;
        #pragma unroll
        for (int k = 0; k < ES; ++k)
            acc += fmaxf(acc1[n * ES + k], 0.f) * w[k * ES + j];
    } else {
        const bf16* w = (const bf16*)W2;
        #pragma unroll
        for (int k = 0; k < ES; ++k)
            acc += fmaxf(acc1[n * ES + k], 0.f) * __bfloat162float(w[k * ES + j]);
    }
    X2[tid] = acc;
}

// out = relu(acc2), stored in whichever dtype the flag says.
__global__ void k_out(const float* __restrict__ acc2,
                      const int* __restrict__ flag,
                      void* __restrict__ out) {
    int tid = blockIdx.x * blockDim.x + threadIdx.x;
    float v = fmaxf(acc2[tid], 0.f);
    if (*flag) ((float*)out)[tid] = v;
    else       ((bf16*)out)[tid] = __float2bfloat16(v);
}

extern "C" void kernel_launch(void* const* d_in, const int* in_sizes, int n_in,
                              void* d_out, int out_size, void* d_ws, size_t ws_size,
                              hipStream_t stream) {
    const int* node_ids = (const int*)d_in[0];
    const int* edges    = (const int*)d_in[1];
    const void* table   = d_in[2];
    const void* W1      = d_in[3];
    const void* b1      = d_in[4];
    const void* W2      = d_in[5];
    const void* b2      = d_in[6];

    // ws layout: [flag 256B][deg u32 NN][acc1 f32 NN*ES][acc2 f32 NN*ES][X f32 NN*ES]
    char* ws = (char*)d_ws;
    int* flag           = (int*)ws;
    unsigned int* deg   = (unsigned int*)(ws + 256);
    float* acc1         = (float*)(ws + 256 + (size_t)NN * 4);
    float* acc2         = acc1 + (size_t)NN * ES;
    float* X            = acc2 + (size_t)NN * ES;   // holds X1, then reused for X2

    // zero flag + deg + acc1 + acc2 (contiguous prefix, ~3.2 MB)
    size_t zbytes = 256 + (size_t)NN * 4 + 2ull * NN * ES * 4;
    hipMemsetAsync(d_ws, 0, zbytes, stream);

    const int B = 256;
    int g_node = (NN * ES) / B;               // 1536 blocks, exact
    int g_edge = (NE * ES + B - 1) / B;       // 3073 blocks

    k_detect <<<1, B, 0, stream>>>(W1, flag);
    k_deg_x1 <<<g_node, B, 0, stream>>>(node_ids, edges, table, W1, b1, flag, deg, X);
    k_scatter<<<g_edge, B, 0, stream>>>(edges, deg, X, acc1);
    k_x2     <<<g_node, B, 0, stream>>>(acc1, W2, b2, flag, X);
    k_scatter<<<g_edge, B, 0, stream>>>(edges, deg, X, acc2);
    k_out    <<<g_node, B, 0, stream>>>(acc2, flag, d_out);
}